// Round 1
// baseline (408.785 us; speedup 1.0000x reference)
//
#include <hip/hip_runtime.h>

#define NEG_SLOPE 0.2f

typedef short s16x8 __attribute__((ext_vector_type(8)));
typedef float f32x4 __attribute__((ext_vector_type(4)));

__device__ __forceinline__ unsigned short f2bf(float f) {
    unsigned int u = __float_as_uint(f);
    unsigned int r = (u + 0x7fffu + ((u >> 16) & 1u)) >> 16;
    return (unsigned short)r;
}
__device__ __forceinline__ float bf2f(unsigned int us) {
    return __uint_as_float(us << 16);
}

// ---------------- count + wl precompute + W split-bf16 transpose-convert ----------------
// block 0: wl1/wl2;  blocks 1-4: W1 -> Bt1 [col][K];  blocks 5-6: W2 -> Bt2;  7+: counting

__global__ void count_wl_k(const int* __restrict__ dst, int* __restrict__ counts, int E,
                           const float* __restrict__ W1, const float* __restrict__ al1,
                           const float* __restrict__ ar1,
                           const float* __restrict__ W2, const float* __restrict__ al2,
                           const float* __restrict__ ar2,
                           float* __restrict__ wl1, float* __restrict__ wl2,
                           unsigned short* __restrict__ Bt1h, unsigned short* __restrict__ Bt1l,
                           unsigned short* __restrict__ Bt2h, unsigned short* __restrict__ Bt2l) {
    const int b = blockIdx.x;
    if (b == 0) {   // block-uniform branch
        int k = threadIdx.x; // 256
        #pragma unroll
        for (int h = 0; h < 4; h++) {
            float sl = 0.f, sr = 0.f;
            #pragma unroll 8
            for (int d = 0; d < 64; d++) {
                float wv = W1[k * 256 + h * 64 + d];
                sl = fmaf(wv, al1[h * 64 + d], sl);
                sr = fmaf(wv, ar1[h * 64 + d], sr);
            }
            wl1[k * 8 + h] = sl;
            wl1[k * 8 + 4 + h] = sr;
        }
        float sl = 0.f, sr = 0.f;
        #pragma unroll 8
        for (int d = 0; d < 128; d++) {
            float wv = W2[k * 128 + d];
            sl = fmaf(wv, al2[d], sl);
            sr = fmaf(wv, ar2[d], sr);
        }
        wl2[k * 2 + 0] = sl;
        wl2[k * 2 + 1] = sr;
        return;
    }
    if (b <= 4) {   // W1 [K=256][256] -> Bt1[col][256] hi/lo
        int c = (b - 1) * 64 + (threadIdx.x >> 2);
        int kq = threadIdx.x & 3;
        #pragma unroll 8
        for (int kk = 0; kk < 64; kk++) {
            int k = kq + kk * 4;
            float w = W1[k * 256 + c];
            unsigned short h = f2bf(w);
            unsigned short l = f2bf(w - bf2f(h));
            Bt1h[c * 256 + k] = h;
            Bt1l[c * 256 + k] = l;
        }
        return;
    }
    if (b <= 6) {   // W2 [K=256][128] -> Bt2[col][256] hi/lo
        int c = (b - 5) * 64 + (threadIdx.x >> 2);
        int kq = threadIdx.x & 3;
        #pragma unroll 8
        for (int kk = 0; kk < 64; kk++) {
            int k = kq + kk * 4;
            float w = W2[k * 128 + c];
            unsigned short h = f2bf(w);
            unsigned short l = f2bf(w - bf2f(h));
            Bt2h[c * 256 + k] = h;
            Bt2l[c * 256 + k] = l;
        }
        return;
    }
    int e = (b - 7) * 256 + threadIdx.x;
    if (e < E) atomicAdd(&counts[dst[e]], 1);
}

// ---------------- single-dispatch scan (publish-then-wait lookback) ----------

__global__ __launch_bounds__(1024) void scan_k(const int* __restrict__ counts,
                                               int* __restrict__ flags,
                                               int* __restrict__ offsets,
                                               int* __restrict__ cursor, int n) {
    __shared__ int s_wt[16];
    __shared__ int s_base;
    const int tid = threadIdx.x, lane = tid & 63, wid = tid >> 6;
    const int bid = blockIdx.x;
    const int i = bid * 1024 + tid;
    int v = (i < n) ? counts[i] : 0;
    int incl = v;
    #pragma unroll
    for (int o = 1; o < 64; o <<= 1) {
        int t = __shfl_up(incl, o);
        if (lane >= o) incl += t;
    }
    if (lane == 63) s_wt[wid] = incl;
    __syncthreads();
    if (tid == 0) {
        int r = 0;
        #pragma unroll
        for (int w = 0; w < 16; w++) { int t = s_wt[w]; s_wt[w] = r; r += t; }
        atomicExch(&flags[bid], r + 1);   // publish block total
        s_base = 0;
    }
    __syncthreads();
    if (wid == 0) {
        int contrib = 0;
        if (lane < bid) {
            int f;
            while ((f = atomicAdd(&flags[lane], 0)) == 0) {}
            contrib = f - 1;
        }
        #pragma unroll
        for (int o = 32; o > 0; o >>= 1) contrib += __shfl_xor(contrib, o);
        if (lane == 0) s_base = contrib;
    }
    __syncthreads();
    if (i < n) {
        int excl = s_base + s_wt[wid] + (incl - v);
        offsets[i + 1] = excl + v;
        cursor[i] = excl;
    }
    if (bid == 0 && tid == 0) offsets[0] = 0;
}

__global__ void fill_csr_k(const int* __restrict__ src, const int* __restrict__ dst,
                           int* __restrict__ cursor, int* __restrict__ csr_src, int E) {
    int e = blockIdx.x * blockDim.x + threadIdx.x;
    if (e < E) {
        int pos = atomicAdd(&cursor[dst[e]], 1);
        csr_src[pos] = src[e];
    }
}

// ---------------- prep: feat -> split-bf16 A + fused el1/er1 ----------------
// one wave per row; lane covers 4 channels (float4). el/er via full-wave shfl reduce.

__global__ __launch_bounds__(256) void prep_k(const float* __restrict__ feat,
                                              const float* __restrict__ wl1,
                                              unsigned short* __restrict__ Ah,
                                              unsigned short* __restrict__ Al,
                                              float* __restrict__ el1,
                                              float* __restrict__ er1, int Nn) {
    const int lane = threadIdx.x & 63, wid = threadIdx.x >> 6;
    const int n = blockIdx.x * 4 + wid;
    if (n >= Nn) return;
    float4 f = ((const float4*)(feat + (size_t)n * 256))[lane];
    unsigned short h0 = f2bf(f.x), h1 = f2bf(f.y), h2 = f2bf(f.z), h3 = f2bf(f.w);
    unsigned short l0 = f2bf(f.x - bf2f(h0)), l1 = f2bf(f.y - bf2f(h1));
    unsigned short l2 = f2bf(f.z - bf2f(h2)), l3 = f2bf(f.w - bf2f(h3));
    uint2 hv, lv;
    hv.x = (unsigned)h0 | ((unsigned)h1 << 16);
    hv.y = (unsigned)h2 | ((unsigned)h3 << 16);
    lv.x = (unsigned)l0 | ((unsigned)l1 << 16);
    lv.y = (unsigned)l2 | ((unsigned)l3 << 16);
    ((uint2*)(Ah + (size_t)n * 256))[lane] = hv;
    ((uint2*)(Al + (size_t)n * 256))[lane] = lv;

    float ff[4] = {f.x, f.y, f.z, f.w};
    float pa[4] = {0.f, 0.f, 0.f, 0.f}, pb[4] = {0.f, 0.f, 0.f, 0.f};
    const float* wp = wl1 + lane * 32;   // k = lane*4 + j ; layout wl1[k*8 + (a:0..3 | b:4..7)]
    #pragma unroll
    for (int j = 0; j < 4; j++) {
        float4 wa = *(const float4*)(wp + j * 8);
        float4 wb = *(const float4*)(wp + j * 8 + 4);
        pa[0] = fmaf(ff[j], wa.x, pa[0]); pa[1] = fmaf(ff[j], wa.y, pa[1]);
        pa[2] = fmaf(ff[j], wa.z, pa[2]); pa[3] = fmaf(ff[j], wa.w, pa[3]);
        pb[0] = fmaf(ff[j], wb.x, pb[0]); pb[1] = fmaf(ff[j], wb.y, pb[1]);
        pb[2] = fmaf(ff[j], wb.z, pb[2]); pb[3] = fmaf(ff[j], wb.w, pb[3]);
    }
    #pragma unroll
    for (int h = 0; h < 4; h++) {
        #pragma unroll
        for (int o = 32; o > 0; o >>= 1) {
            pa[h] += __shfl_xor(pa[h], o);
            pb[h] += __shfl_xor(pb[h], o);
        }
    }
    if (lane == 0) {
        ((float4*)el1)[n] = float4{pa[0], pa[1], pa[2], pa[3]};
        ((float4*)er1)[n] = float4{pb[0], pb[1], pb[2], pb[3]};
    }
}

// ---------------- pure split-bf16 MFMA GEMM (pre-converted operands) ----------------
// 128x64 tile, K=256 (8 steps). Reg-staged LDS, pad 56 (16B-aligned rows, 8-distinct
// bank offsets). Next tile's global loads issued before the MFMA cluster.

__global__ __launch_bounds__(256) void gemm_k(const unsigned short* __restrict__ Ah,
                                              const unsigned short* __restrict__ Al,
                                              const unsigned short* __restrict__ Bh,
                                              const unsigned short* __restrict__ Bl,
                                              unsigned short* __restrict__ Cb,
                                              int M, int Nc) {
    __shared__ __align__(16) unsigned short As_h[128][56], As_l[128][56];
    __shared__ __align__(16) unsigned short Bs_h[64][56], Bs_l[64][56];

    const int tid = threadIdx.x;
    const int lane = tid & 63, wid = tid >> 6;
    const int row0 = blockIdx.y * 128;
    const int col0 = blockIdx.x * 64;     // x fastest -> A-tile shared by adjacent blocks
    const int wm = (wid & 1) * 64;
    const int wn = (wid >> 1) * 32;
    const int quad = lane >> 4, mrow = lane & 15;

    const int a_row = tid >> 1;           // 0..127
    const int a_k = (tid & 1) * 16;       // {0,16}
    const int b_col = tid >> 2;           // 0..63
    const int b_k = (tid & 3) * 8;        // {0,8,16,24}

    const size_t a_off = (size_t)min(row0 + a_row, M - 1) * 256 + a_k;
    const size_t b_off = (size_t)(col0 + b_col) * 256 + b_k;

    f32x4 acc[4][2];
    #pragma unroll
    for (int i = 0; i < 4; i++)
        #pragma unroll
        for (int j = 0; j < 2; j++) acc[i][j] = f32x4{0.f, 0.f, 0.f, 0.f};

    uint4 rah0 = *(const uint4*)(Ah + a_off);
    uint4 rah1 = *(const uint4*)(Ah + a_off + 8);
    uint4 ral0 = *(const uint4*)(Al + a_off);
    uint4 ral1 = *(const uint4*)(Al + a_off + 8);
    uint4 rbh  = *(const uint4*)(Bh + b_off);
    uint4 rbl  = *(const uint4*)(Bl + b_off);

    for (int kt = 0; kt < 8; kt++) {
        __syncthreads();                       // prev iter's frag reads complete
        *(uint4*)&As_h[a_row][a_k]     = rah0;
        *(uint4*)&As_h[a_row][a_k + 8] = rah1;
        *(uint4*)&As_l[a_row][a_k]     = ral0;
        *(uint4*)&As_l[a_row][a_k + 8] = ral1;
        *(uint4*)&Bs_h[b_col][b_k] = rbh;
        *(uint4*)&Bs_l[b_col][b_k] = rbl;
        __syncthreads();
        if (kt < 7) {                          // prefetch next K-tile under MFMA
            size_t ao = a_off + (size_t)(kt + 1) * 32;
            size_t bo = b_off + (size_t)(kt + 1) * 32;
            rah0 = *(const uint4*)(Ah + ao);
            rah1 = *(const uint4*)(Ah + ao + 8);
            ral0 = *(const uint4*)(Al + ao);
            ral1 = *(const uint4*)(Al + ao + 8);
            rbh  = *(const uint4*)(Bh + bo);
            rbl  = *(const uint4*)(Bl + bo);
        }
        s16x8 ah[4], al4[4], bh[2], bl[2];
        #pragma unroll
        for (int i = 0; i < 4; i++) {
            ah[i]  = *(const s16x8*)&As_h[wm + 16 * i + mrow][quad * 8];
            al4[i] = *(const s16x8*)&As_l[wm + 16 * i + mrow][quad * 8];
        }
        #pragma unroll
        for (int j = 0; j < 2; j++) {
            bh[j] = *(const s16x8*)&Bs_h[wn + 16 * j + mrow][quad * 8];
            bl[j] = *(const s16x8*)&Bs_l[wn + 16 * j + mrow][quad * 8];
        }
        #pragma unroll
        for (int i = 0; i < 4; i++)
            #pragma unroll
            for (int j = 0; j < 2; j++) {
                acc[i][j] = __builtin_amdgcn_mfma_f32_16x16x32_bf16(ah[i],  bh[j], acc[i][j], 0, 0, 0);
                acc[i][j] = __builtin_amdgcn_mfma_f32_16x16x32_bf16(ah[i],  bl[j], acc[i][j], 0, 0, 0);
                acc[i][j] = __builtin_amdgcn_mfma_f32_16x16x32_bf16(al4[i], bh[j], acc[i][j], 0, 0, 0);
            }
    }

    #pragma unroll
    for (int i = 0; i < 4; i++) {
        #pragma unroll
        for (int j = 0; j < 2; j++) {
            int col = col0 + wn + 16 * j + mrow;
            int rbase = row0 + wm + 16 * i + quad * 4;
            #pragma unroll
            for (int r = 0; r < 4; r++) {
                int row = rbase + r;
                if (row < M) Cb[(size_t)row * Nc + col] = f2bf(acc[i][j][r]);
            }
        }
    }
}

// ---------------- fused edge-softmax + wide-row gather-aggregate ----------------
// one WAVE per node. FUSE2: layer-1 epilogue emits split-bf16 h1 + el2/er2 (no fp32 h1).

__device__ __forceinline__ void fma8(float* acc, float wgt, uint4 u) {
    acc[0] = fmaf(wgt, bf2f(u.x & 0xffff), acc[0]);
    acc[1] = fmaf(wgt, bf2f(u.x >> 16),    acc[1]);
    acc[2] = fmaf(wgt, bf2f(u.y & 0xffff), acc[2]);
    acc[3] = fmaf(wgt, bf2f(u.y >> 16),    acc[3]);
    acc[4] = fmaf(wgt, bf2f(u.z & 0xffff), acc[4]);
    acc[5] = fmaf(wgt, bf2f(u.z >> 16),    acc[5]);
    acc[6] = fmaf(wgt, bf2f(u.w & 0xffff), acc[6]);
    acc[7] = fmaf(wgt, bf2f(u.w >> 16),    acc[7]);
}

template <int H, int D, bool RELU, bool FUSE2>
__global__ __launch_bounds__(256) void fagg_k(const unsigned short* __restrict__ ft,
                                              const float* __restrict__ el,
                                              const float* __restrict__ er,
                                              const int* __restrict__ offsets,
                                              const int* __restrict__ csr_src,
                                              const float* __restrict__ bias,
                                              float* __restrict__ out, int n_nodes,
                                              unsigned short* __restrict__ oh,
                                              unsigned short* __restrict__ ol,
                                              const float* __restrict__ wl2,
                                              float* __restrict__ el2,
                                              float* __restrict__ er2) {
    constexpr int HD = H * D;
    constexpr int LPE = HD / 8;    // lanes per edge-row (16B/lane): 32 (L1), 16 (L2)
    constexpr int EPI = 64 / LPE;  // edges per wave-load: 2 (L1), 4 (L2)
    const int lane = threadIdx.x & 63;
    const int w = threadIdx.x >> 6;
    const int n = blockIdx.x * 4 + w;
    __shared__ int   s_src[4][64];
    __shared__ float s_a[4][64 * H];
    if (n >= n_nodes) return;
    const int off = offsets[n];
    const int deg = offsets[n + 1] - off;
    const int lane_sub = lane & (LPE - 1);
    const int q = lane / LPE;          // which of the EPI edges this lane serves
    const int c0 = lane_sub * 8;
    const int h_of = c0 / D;

    float ern[H];
    #pragma unroll
    for (int h = 0; h < H; h++) ern[h] = er[n * H + h];

    float acc[8];
    #pragma unroll
    for (int t = 0; t < 8; t++) acc[t] = 0.f;

    const int* s_src_w = s_src[w];
    const float* s_a_w = s_a[w];
    const uint4* fp = ((const uint4*)ft) + lane_sub;

    if (deg <= 64) {
        // ---- fast path: all edges in one wave pass ----
        const bool act = lane < deg;
        int sv = act ? csr_src[off + lane] : 0;
        s_src[w][lane] = sv;
        float evr[H];
        if constexpr (H == 4) {
            float4 e4 = ((const float4*)el)[sv];
            evr[0] = e4.x; evr[1] = e4.y; evr[2] = e4.z; evr[3] = e4.w;
        } else {
            evr[0] = el[sv];
        }
        int p0, p1, p2, p3;
        {
            p0 = s_src_w[q]; p1 = s_src_w[EPI + q];
            p2 = s_src_w[2 * EPI + q]; p3 = s_src_w[3 * EPI + q];
        }
        uint4 u0 = fp[(size_t)p0 * LPE];
        uint4 u1 = fp[(size_t)p1 * LPE];
        uint4 u2 = fp[(size_t)p2 * LPE];
        uint4 u3 = fp[(size_t)p3 * LPE];
        float ev[H], m[H];
        #pragma unroll
        for (int h = 0; h < H; h++) {
            float t = evr[h] + ern[h];
            t = t > 0.f ? t : NEG_SLOPE * t;
            ev[h] = act ? t : -1e30f;
            m[h] = ev[h];
        }
        #pragma unroll
        for (int h = 0; h < H; h++)
            for (int o = 32; o > 0; o >>= 1) m[h] = fmaxf(m[h], __shfl_xor(m[h], o));
        float ex[H], sm[H];
        #pragma unroll
        for (int h = 0; h < H; h++) { ex[h] = act ? __expf(ev[h] - m[h]) : 0.f; sm[h] = ex[h]; }
        #pragma unroll
        for (int h = 0; h < H; h++)
            for (int o = 32; o > 0; o >>= 1) sm[h] += __shfl_xor(sm[h], o);
        #pragma unroll
        for (int h = 0; h < H; h++)
            s_a[w][lane * H + h] = ex[h] * (sm[h] > 0.f ? 1.f / sm[h] : 0.f);
        fma8(acc, s_a_w[(q) * H + h_of], u0);
        fma8(acc, s_a_w[(EPI + q) * H + h_of], u1);
        fma8(acc, s_a_w[(2 * EPI + q) * H + h_of], u2);
        fma8(acc, s_a_w[(3 * EPI + q) * H + h_of], u3);
        const int rc = (deg + EPI - 1) & ~(EPI - 1);
        int i = 4 * EPI;
        for (; i + 4 * EPI <= rc; i += 4 * EPI) {
            int e0 = i + q, e1 = i + EPI + q, e2 = i + 2 * EPI + q, e3 = i + 3 * EPI + q;
            int s0 = s_src_w[e0], s1 = s_src_w[e1], s2 = s_src_w[e2], s3 = s_src_w[e3];
            uint4 v0 = fp[(size_t)s0 * LPE];
            uint4 v1 = fp[(size_t)s1 * LPE];
            uint4 v2 = fp[(size_t)s2 * LPE];
            uint4 v3 = fp[(size_t)s3 * LPE];
            float w0 = s_a_w[e0 * H + h_of], w1 = s_a_w[e1 * H + h_of];
            float w2 = s_a_w[e2 * H + h_of], w3 = s_a_w[e3 * H + h_of];
            fma8(acc, w0, v0); fma8(acc, w1, v1); fma8(acc, w2, v2); fma8(acc, w3, v3);
        }
        for (; i < rc; i += EPI) {
            int e = i + q;
            int s = s_src_w[e];
            uint4 v = fp[(size_t)s * LPE];
            fma8(acc, s_a_w[e * H + h_of], v);
        }
    } else {
        // ---- rare slow path: two-pass softmax, then 64-edge chunks ----
        float m[H];
        #pragma unroll
        for (int h = 0; h < H; h++) m[h] = -1e30f;
        for (int i = lane; i < deg; i += 64) {
            int sv = csr_src[off + i];
            if constexpr (H == 4) {
                float4 e4 = ((const float4*)el)[sv];
                float tmp[4] = {e4.x, e4.y, e4.z, e4.w};
                #pragma unroll
                for (int h = 0; h < 4; h++) {
                    float t = tmp[h] + ern[h];
                    t = t > 0.f ? t : NEG_SLOPE * t;
                    m[h] = fmaxf(m[h], t);
                }
            } else {
                float t = el[sv] + ern[0];
                t = t > 0.f ? t : NEG_SLOPE * t;
                m[0] = fmaxf(m[0], t);
            }
        }
        #pragma unroll
        for (int h = 0; h < H; h++)
            for (int o = 32; o > 0; o >>= 1) m[h] = fmaxf(m[h], __shfl_xor(m[h], o));
        float sm[H];
        #pragma unroll
        for (int h = 0; h < H; h++) sm[h] = 0.f;
        for (int i = lane; i < deg; i += 64) {
            int sv = csr_src[off + i];
            if constexpr (H == 4) {
                float4 e4 = ((const float4*)el)[sv];
                float tmp[4] = {e4.x, e4.y, e4.z, e4.w};
                #pragma unroll
                for (int h = 0; h < 4; h++) {
                    float t = tmp[h] + ern[h];
                    t = t > 0.f ? t : NEG_SLOPE * t;
                    sm[h] += __expf(t - m[h]);
                }
            } else {
                float t = el[sv] + ern[0];
                t = t > 0.f ? t : NEG_SLOPE * t;
                sm[0] += __expf(t - m[0]);
            }
        }
        #pragma unroll
        for (int h = 0; h < H; h++)
            for (int o = 32; o > 0; o >>= 1) sm[h] += __shfl_xor(sm[h], o);
        float inv[H];
        #pragma unroll
        for (int h = 0; h < H; h++) inv[h] = (sm[h] > 0.f) ? (1.f / sm[h]) : 0.f;
        for (int base = 0; base < deg; base += 64) {
            const bool act2 = base + lane < deg;
            int sv = act2 ? csr_src[off + base + lane] : 0;
            s_src[w][lane] = sv;
            float exh[H];
            if constexpr (H == 4) {
                float4 e4 = ((const float4*)el)[sv];
                float tmp[4] = {e4.x, e4.y, e4.z, e4.w};
                #pragma unroll
                for (int h = 0; h < 4; h++) {
                    float t = tmp[h] + ern[h];
                    t = t > 0.f ? t : NEG_SLOPE * t;
                    exh[h] = act2 ? __expf(t - m[h]) * inv[h] : 0.f;
                }
            } else {
                float t = el[sv] + ern[0];
                t = t > 0.f ? t : NEG_SLOPE * t;
                exh[0] = act2 ? __expf(t - m[0]) * inv[0] : 0.f;
            }
            #pragma unroll
            for (int h = 0; h < H; h++) s_a[w][lane * H + h] = exh[h];
            int cnt = min(64, deg - base);
            int rc = (cnt + EPI - 1) & ~(EPI - 1);
            int i = 0;
            for (; i + 4 * EPI <= rc; i += 4 * EPI) {
                int e0 = i + q, e1 = i + EPI + q, e2 = i + 2 * EPI + q, e3 = i + 3 * EPI + q;
                int s0 = s_src_w[e0], s1 = s_src_w[e1], s2 = s_src_w[e2], s3 = s_src_w[e3];
                uint4 v0 = fp[(size_t)s0 * LPE];
                uint4 v1 = fp[(size_t)s1 * LPE];
                uint4 v2 = fp[(size_t)s2 * LPE];
                uint4 v3 = fp[(size_t)s3 * LPE];
                float w0 = s_a_w[e0 * H + h_of], w1 = s_a_w[e1 * H + h_of];
                float w2 = s_a_w[e2 * H + h_of], w3 = s_a_w[e3 * H + h_of];
                fma8(acc, w0, v0); fma8(acc, w1, v1); fma8(acc, w2, v2); fma8(acc, w3, v3);
            }
            for (; i < rc; i += EPI) {
                int e = i + q;
                int s = s_src_w[e];
                uint4 v = fp[(size_t)s * LPE];
                fma8(acc, s_a_w[e * H + h_of], v);
            }
        }
    }

    // cross-lane combine: edge sub-groups fold into lanes [0, LPE)
    #pragma unroll
    for (int t = 0; t < 8; t++) {
        #pragma unroll
        for (int s = LPE; s < 64; s <<= 1) acc[t] += __shfl_xor(acc[t], s);
    }
    if (lane < LPE) {
        float4 b0 = ((const float4*)bias)[lane * 2];
        float4 b1 = ((const float4*)bias)[lane * 2 + 1];
        float v[8] = {acc[0] + b0.x, acc[1] + b0.y, acc[2] + b0.z, acc[3] + b0.w,
                      acc[4] + b1.x, acc[5] + b1.y, acc[6] + b1.z, acc[7] + b1.w};
        if (RELU) {
            #pragma unroll
            for (int t = 0; t < 8; t++) v[t] = fmaxf(v[t], 0.f);
        }
        if constexpr (FUSE2) {
            // split-bf16 h1 directly (layer-2 GEMM A operand) + fused el2/er2
            unsigned short hh[8], ll[8];
            #pragma unroll
            for (int t = 0; t < 8; t++) {
                hh[t] = f2bf(v[t]);
                ll[t] = f2bf(v[t] - bf2f(hh[t]));
            }
            uint4 hv, lv;
            hv.x = (unsigned)hh[0] | ((unsigned)hh[1] << 16);
            hv.y = (unsigned)hh[2] | ((unsigned)hh[3] << 16);
            hv.z = (unsigned)hh[4] | ((unsigned)hh[5] << 16);
            hv.w = (unsigned)hh[6] | ((unsigned)hh[7] << 16);
            lv.x = (unsigned)ll[0] | ((unsigned)ll[1] << 16);
            lv.y = (unsigned)ll[2] | ((unsigned)ll[3] << 16);
            lv.z = (unsigned)ll[4] | ((unsigned)ll[5] << 16);
            lv.w = (unsigned)ll[6] | ((unsigned)ll[7] << 16);
            ((uint4*)(oh + (size_t)n * HD))[lane] = hv;
            ((uint4*)(ol + (size_t)n * HD))[lane] = lv;
            float pa = 0.f, pb = 0.f;
            #pragma unroll
            for (int t = 0; t < 8; t++) {
                float2 wv = ((const float2*)wl2)[lane * 8 + t];
                pa = fmaf(v[t], wv.x, pa);
                pb = fmaf(v[t], wv.y, pb);
            }
            #pragma unroll
            for (int o = 16; o > 0; o >>= 1) {
                pa += __shfl_xor(pa, o);
                pb += __shfl_xor(pb, o);
            }
            if (lane == 0) { el2[n] = pa; er2[n] = pb; }
        } else {
            float4 o0{v[0], v[1], v[2], v[3]};
            float4 o1{v[4], v[5], v[6], v[7]};
            float4* op = (float4*)out + (size_t)n * (HD / 4) + lane * 2;
            op[0] = o0;
            op[1] = o1;
        }
    }
}

// ---------------- launch ----------------

extern "C" void kernel_launch(void* const* d_in, const int* in_sizes, int n_in,
                              void* d_out, int out_size, void* d_ws, size_t ws_size,
                              hipStream_t stream) {
    const float* feat    = (const float*)d_in[0];
    const int*   src     = (const int*)d_in[1];
    const int*   dst     = (const int*)d_in[2];
    const float* W1      = (const float*)d_in[3];
    const float* attn_l1 = (const float*)d_in[4];
    const float* attn_r1 = (const float*)d_in[5];
    const float* bias1   = (const float*)d_in[6];
    const float* W2      = (const float*)d_in[7];
    const float* attn_l2 = (const float*)d_in[8];
    const float* attn_r2 = (const float*)d_in[9];
    const float* bias2   = (const float*)d_in[10];
    float* out = (float*)d_out;

    const int N = in_sizes[0] / 256;   // 50000
    const int E = in_sizes[1];         // 800000
    const int NB = (N + 1023) / 1024;  // 49 (<= 64 for lookback wave)

    char* ws = (char*)d_ws;
    size_t o = 0;
    auto alloc = [&](size_t bytes) -> void* {
        void* p = ws + o;
        o = (o + bytes + 255) & ~(size_t)255;
        return p;
    };
    int* counts  = (int*)alloc((size_t)(N + 64) * 4);
    int* flags   = counts + N;
    int* cursor  = (int*)alloc((size_t)N * 4);
    int* offsets = (int*)alloc((size_t)(N + 1) * 4);
    int* csr_src = (int*)alloc((size_t)E * 4);
    float* wl1 = (float*)alloc(256 * 8 * 4);
    float* wl2 = (float*)alloc(256 * 2 * 4);
    float* el1 = (float*)alloc((size_t)N * 4 * 4);
    float* er1 = (float*)alloc((size_t)N * 4 * 4);
    float* el2 = (float*)alloc((size_t)N * 4);
    float* er2 = (float*)alloc((size_t)N * 4);
    unsigned short* ft1b = (unsigned short*)alloc((size_t)N * 256 * 2);
    unsigned short* Ah   = (unsigned short*)alloc((size_t)N * 256 * 2);
    unsigned short* Al   = (unsigned short*)alloc((size_t)N * 256 * 2);
    unsigned short* Bt1h = (unsigned short*)alloc((size_t)256 * 256 * 2);
    unsigned short* Bt1l = (unsigned short*)alloc((size_t)256 * 256 * 2);
    unsigned short* Bt2h = (unsigned short*)alloc((size_t)128 * 256 * 2);
    unsigned short* Bt2l = (unsigned short*)alloc((size_t)128 * 256 * 2);
    unsigned short* ft2b = ft1b;   // ft1b dead after layer-1 aggregation
    unsigned short* h1h  = Ah;     // feat split-bf16 dead after layer-1 GEMM
    unsigned short* h1l  = Al;

    hipMemsetAsync(counts, 0, (size_t)(N + 64) * 4, stream);
    count_wl_k<<<7 + (E + 255) / 256, 256, 0, stream>>>(dst, counts, E,
        W1, attn_l1, attn_r1, W2, attn_l2, attn_r2, wl1, wl2, Bt1h, Bt1l, Bt2h, Bt2l);
    scan_k<<<NB, 1024, 0, stream>>>(counts, flags, offsets, cursor, N);
    fill_csr_k<<<(E + 255) / 256, 256, 0, stream>>>(src, dst, cursor, csr_src, E);
    prep_k<<<(N + 3) / 4, 256, 0, stream>>>(feat, wl1, Ah, Al, el1, er1, N);

    // layer 1: H=4, D=64
    gemm_k<<<dim3(4, (N + 127) / 128), 256, 0, stream>>>(Ah, Al, Bt1h, Bt1l, ft1b, N, 256);
    fagg_k<4, 64, true, true><<<(N + 3) / 4, 256, 0, stream>>>(ft1b, el1, er1, offsets, csr_src,
                                                               bias1, nullptr, N,
                                                               h1h, h1l, wl2, el2, er2);

    // layer 2: H=1, D=128
    gemm_k<<<dim3(2, (N + 127) / 128), 256, 0, stream>>>(h1h, h1l, Bt2h, Bt2l, ft2b, N, 128);
    fagg_k<1, 128, false, false><<<(N + 3) / 4, 256, 0, stream>>>(ft2b, el2, er2, offsets, csr_src,
                                                                  bias2, out, N,
                                                                  nullptr, nullptr, nullptr,
                                                                  nullptr, nullptr);
}

// Round 2
// 402.907 us; speedup vs baseline: 1.0146x; 1.0146x over previous
//
#include <hip/hip_runtime.h>

#define NEG_SLOPE 0.2f

typedef short s16x8 __attribute__((ext_vector_type(8)));
typedef float f32x4 __attribute__((ext_vector_type(4)));

__device__ __forceinline__ unsigned short f2bf(float f) {
    unsigned int u = __float_as_uint(f);
    unsigned int r = (u + 0x7fffu + ((u >> 16) & 1u)) >> 16;
    return (unsigned short)r;
}
__device__ __forceinline__ float bf2f(unsigned int us) {
    return __uint_as_float(us << 16);
}

// ---------------- count + wl precompute + W split-bf16 transpose-convert ----------------
// block 0: wl1/wl2;  blocks 1-4: W1 -> Bt1 [col][K];  blocks 5-6: W2 -> Bt2;  7+: counting

__global__ void count_wl_k(const int* __restrict__ dst, int* __restrict__ counts, int E,
                           const float* __restrict__ W1, const float* __restrict__ al1,
                           const float* __restrict__ ar1,
                           const float* __restrict__ W2, const float* __restrict__ al2,
                           const float* __restrict__ ar2,
                           float* __restrict__ wl1, float* __restrict__ wl2,
                           unsigned short* __restrict__ Bt1h, unsigned short* __restrict__ Bt1l,
                           unsigned short* __restrict__ Bt2h, unsigned short* __restrict__ Bt2l) {
    const int b = blockIdx.x;
    if (b == 0) {   // block-uniform branch
        int k = threadIdx.x; // 256
        #pragma unroll
        for (int h = 0; h < 4; h++) {
            float sl = 0.f, sr = 0.f;
            #pragma unroll 8
            for (int d = 0; d < 64; d++) {
                float wv = W1[k * 256 + h * 64 + d];
                sl = fmaf(wv, al1[h * 64 + d], sl);
                sr = fmaf(wv, ar1[h * 64 + d], sr);
            }
            wl1[k * 8 + h] = sl;
            wl1[k * 8 + 4 + h] = sr;
        }
        float sl = 0.f, sr = 0.f;
        #pragma unroll 8
        for (int d = 0; d < 128; d++) {
            float wv = W2[k * 128 + d];
            sl = fmaf(wv, al2[d], sl);
            sr = fmaf(wv, ar2[d], sr);
        }
        wl2[k * 2 + 0] = sl;
        wl2[k * 2 + 1] = sr;
        return;
    }
    if (b <= 4) {   // W1 [K=256][256] -> Bt1[col][256] hi/lo
        int c = (b - 1) * 64 + (threadIdx.x >> 2);
        int kq = threadIdx.x & 3;
        #pragma unroll 8
        for (int kk = 0; kk < 64; kk++) {
            int k = kq + kk * 4;
            float w = W1[k * 256 + c];
            unsigned short h = f2bf(w);
            unsigned short l = f2bf(w - bf2f(h));
            Bt1h[c * 256 + k] = h;
            Bt1l[c * 256 + k] = l;
        }
        return;
    }
    if (b <= 6) {   // W2 [K=256][128] -> Bt2[col][256] hi/lo
        int c = (b - 5) * 64 + (threadIdx.x >> 2);
        int kq = threadIdx.x & 3;
        #pragma unroll 8
        for (int kk = 0; kk < 64; kk++) {
            int k = kq + kk * 4;
            float w = W2[k * 128 + c];
            unsigned short h = f2bf(w);
            unsigned short l = f2bf(w - bf2f(h));
            Bt2h[c * 256 + k] = h;
            Bt2l[c * 256 + k] = l;
        }
        return;
    }
    int e = (b - 7) * 256 + threadIdx.x;
    if (e < E) atomicAdd(&counts[dst[e]], 1);
}

// ---------------- single-dispatch scan (publish-then-wait lookback) ----------

__global__ __launch_bounds__(1024) void scan_k(const int* __restrict__ counts,
                                               int* __restrict__ flags,
                                               int* __restrict__ offsets,
                                               int* __restrict__ cursor, int n) {
    __shared__ int s_wt[16];
    __shared__ int s_base;
    const int tid = threadIdx.x, lane = tid & 63, wid = tid >> 6;
    const int bid = blockIdx.x;
    const int i = bid * 1024 + tid;
    int v = (i < n) ? counts[i] : 0;
    int incl = v;
    #pragma unroll
    for (int o = 1; o < 64; o <<= 1) {
        int t = __shfl_up(incl, o);
        if (lane >= o) incl += t;
    }
    if (lane == 63) s_wt[wid] = incl;
    __syncthreads();
    if (tid == 0) {
        int r = 0;
        #pragma unroll
        for (int w = 0; w < 16; w++) { int t = s_wt[w]; s_wt[w] = r; r += t; }
        atomicExch(&flags[bid], r + 1);   // publish block total
        s_base = 0;
    }
    __syncthreads();
    if (wid == 0) {
        int contrib = 0;
        if (lane < bid) {
            int f;
            while ((f = atomicAdd(&flags[lane], 0)) == 0) {}
            contrib = f - 1;
        }
        #pragma unroll
        for (int o = 32; o > 0; o >>= 1) contrib += __shfl_xor(contrib, o);
        if (lane == 0) s_base = contrib;
    }
    __syncthreads();
    if (i < n) {
        int excl = s_base + s_wt[wid] + (incl - v);
        offsets[i + 1] = excl + v;
        cursor[i] = excl;
    }
    if (bid == 0 && tid == 0) offsets[0] = 0;
}

__global__ void fill_csr_k(const int* __restrict__ src, const int* __restrict__ dst,
                           int* __restrict__ cursor, int* __restrict__ csr_src, int E) {
    int e = blockIdx.x * blockDim.x + threadIdx.x;
    if (e < E) {
        int pos = atomicAdd(&cursor[dst[e]], 1);
        csr_src[pos] = src[e];
    }
}

// ---------------- prep: feat -> split-bf16 A + fused el1/er1 ----------------

__global__ __launch_bounds__(256) void prep_k(const float* __restrict__ feat,
                                              const float* __restrict__ wl1,
                                              unsigned short* __restrict__ Ah,
                                              unsigned short* __restrict__ Al,
                                              float* __restrict__ el1,
                                              float* __restrict__ er1, int Nn) {
    const int lane = threadIdx.x & 63, wid = threadIdx.x >> 6;
    const int n = blockIdx.x * 4 + wid;
    if (n >= Nn) return;
    float4 f = ((const float4*)(feat + (size_t)n * 256))[lane];
    unsigned short h0 = f2bf(f.x), h1 = f2bf(f.y), h2 = f2bf(f.z), h3 = f2bf(f.w);
    unsigned short l0 = f2bf(f.x - bf2f(h0)), l1 = f2bf(f.y - bf2f(h1));
    unsigned short l2 = f2bf(f.z - bf2f(h2)), l3 = f2bf(f.w - bf2f(h3));
    uint2 hv, lv;
    hv.x = (unsigned)h0 | ((unsigned)h1 << 16);
    hv.y = (unsigned)h2 | ((unsigned)h3 << 16);
    lv.x = (unsigned)l0 | ((unsigned)l1 << 16);
    lv.y = (unsigned)l2 | ((unsigned)l3 << 16);
    ((uint2*)(Ah + (size_t)n * 256))[lane] = hv;
    ((uint2*)(Al + (size_t)n * 256))[lane] = lv;

    float ff[4] = {f.x, f.y, f.z, f.w};
    float pa[4] = {0.f, 0.f, 0.f, 0.f}, pb[4] = {0.f, 0.f, 0.f, 0.f};
    const float* wp = wl1 + lane * 32;
    #pragma unroll
    for (int j = 0; j < 4; j++) {
        float4 wa = *(const float4*)(wp + j * 8);
        float4 wb = *(const float4*)(wp + j * 8 + 4);
        pa[0] = fmaf(ff[j], wa.x, pa[0]); pa[1] = fmaf(ff[j], wa.y, pa[1]);
        pa[2] = fmaf(ff[j], wa.z, pa[2]); pa[3] = fmaf(ff[j], wa.w, pa[3]);
        pb[0] = fmaf(ff[j], wb.x, pb[0]); pb[1] = fmaf(ff[j], wb.y, pb[1]);
        pb[2] = fmaf(ff[j], wb.z, pb[2]); pb[3] = fmaf(ff[j], wb.w, pb[3]);
    }
    #pragma unroll
    for (int h = 0; h < 4; h++) {
        #pragma unroll
        for (int o = 32; o > 0; o >>= 1) {
            pa[h] += __shfl_xor(pa[h], o);
            pb[h] += __shfl_xor(pb[h], o);
        }
    }
    if (lane == 0) {
        ((float4*)el1)[n] = float4{pa[0], pa[1], pa[2], pa[3]};
        ((float4*)er1)[n] = float4{pb[0], pb[1], pb[2], pb[3]};
    }
}

// ---------------- pure split-bf16 MFMA GEMM (pre-converted operands) ----------------

__global__ __launch_bounds__(256) void gemm_k(const unsigned short* __restrict__ Ah,
                                              const unsigned short* __restrict__ Al,
                                              const unsigned short* __restrict__ Bh,
                                              const unsigned short* __restrict__ Bl,
                                              unsigned short* __restrict__ Cb,
                                              int M, int Nc) {
    __shared__ __align__(16) unsigned short As_h[128][56], As_l[128][56];
    __shared__ __align__(16) unsigned short Bs_h[64][56], Bs_l[64][56];

    const int tid = threadIdx.x;
    const int lane = tid & 63, wid = tid >> 6;
    const int row0 = blockIdx.y * 128;
    const int col0 = blockIdx.x * 64;
    const int wm = (wid & 1) * 64;
    const int wn = (wid >> 1) * 32;
    const int quad = lane >> 4, mrow = lane & 15;

    const int a_row = tid >> 1;
    const int a_k = (tid & 1) * 16;
    const int b_col = tid >> 2;
    const int b_k = (tid & 3) * 8;

    const size_t a_off = (size_t)min(row0 + a_row, M - 1) * 256 + a_k;
    const size_t b_off = (size_t)(col0 + b_col) * 256 + b_k;

    f32x4 acc[4][2];
    #pragma unroll
    for (int i = 0; i < 4; i++)
        #pragma unroll
        for (int j = 0; j < 2; j++) acc[i][j] = f32x4{0.f, 0.f, 0.f, 0.f};

    uint4 rah0 = *(const uint4*)(Ah + a_off);
    uint4 rah1 = *(const uint4*)(Ah + a_off + 8);
    uint4 ral0 = *(const uint4*)(Al + a_off);
    uint4 ral1 = *(const uint4*)(Al + a_off + 8);
    uint4 rbh  = *(const uint4*)(Bh + b_off);
    uint4 rbl  = *(const uint4*)(Bl + b_off);

    for (int kt = 0; kt < 8; kt++) {
        __syncthreads();
        *(uint4*)&As_h[a_row][a_k]     = rah0;
        *(uint4*)&As_h[a_row][a_k + 8] = rah1;
        *(uint4*)&As_l[a_row][a_k]     = ral0;
        *(uint4*)&As_l[a_row][a_k + 8] = ral1;
        *(uint4*)&Bs_h[b_col][b_k] = rbh;
        *(uint4*)&Bs_l[b_col][b_k] = rbl;
        __syncthreads();
        if (kt < 7) {
            size_t ao = a_off + (size_t)(kt + 1) * 32;
            size_t bo = b_off + (size_t)(kt + 1) * 32;
            rah0 = *(const uint4*)(Ah + ao);
            rah1 = *(const uint4*)(Ah + ao + 8);
            ral0 = *(const uint4*)(Al + ao);
            ral1 = *(const uint4*)(Al + ao + 8);
            rbh  = *(const uint4*)(Bh + bo);
            rbl  = *(const uint4*)(Bl + bo);
        }
        s16x8 ah[4], al4[4], bh[2], bl[2];
        #pragma unroll
        for (int i = 0; i < 4; i++) {
            ah[i]  = *(const s16x8*)&As_h[wm + 16 * i + mrow][quad * 8];
            al4[i] = *(const s16x8*)&As_l[wm + 16 * i + mrow][quad * 8];
        }
        #pragma unroll
        for (int j = 0; j < 2; j++) {
            bh[j] = *(const s16x8*)&Bs_h[wn + 16 * j + mrow][quad * 8];
            bl[j] = *(const s16x8*)&Bs_l[wn + 16 * j + mrow][quad * 8];
        }
        #pragma unroll
        for (int i = 0; i < 4; i++)
            #pragma unroll
            for (int j = 0; j < 2; j++) {
                acc[i][j] = __builtin_amdgcn_mfma_f32_16x16x32_bf16(ah[i],  bh[j], acc[i][j], 0, 0, 0);
                acc[i][j] = __builtin_amdgcn_mfma_f32_16x16x32_bf16(ah[i],  bl[j], acc[i][j], 0, 0, 0);
                acc[i][j] = __builtin_amdgcn_mfma_f32_16x16x32_bf16(al4[i], bh[j], acc[i][j], 0, 0, 0);
            }
    }

    #pragma unroll
    for (int i = 0; i < 4; i++) {
        #pragma unroll
        for (int j = 0; j < 2; j++) {
            int col = col0 + wn + 16 * j + mrow;
            int rbase = row0 + wm + 16 * i + quad * 4;
            #pragma unroll
            for (int r = 0; r < 4; r++) {
                int row = rbase + r;
                if (row < M) Cb[(size_t)row * Nc + col] = f2bf(acc[i][j][r]);
            }
        }
    }
}

// ---------------- fused edge-softmax + wide-row gather-aggregate ----------------
// one WAVE per node. Rolling 8-deep gather pipeline: first 8 loads issued before
// the softmax (latency hidden under shuffles); consume loop issues load i+8 as
// load i is consumed. 32-bit saddr offsets (uniform base + v_off).

__device__ __forceinline__ void fma8(float* acc, float wgt, uint4 u) {
    acc[0] = fmaf(wgt, bf2f(u.x & 0xffff), acc[0]);
    acc[1] = fmaf(wgt, bf2f(u.x >> 16),    acc[1]);
    acc[2] = fmaf(wgt, bf2f(u.y & 0xffff), acc[2]);
    acc[3] = fmaf(wgt, bf2f(u.y >> 16),    acc[3]);
    acc[4] = fmaf(wgt, bf2f(u.z & 0xffff), acc[4]);
    acc[5] = fmaf(wgt, bf2f(u.z >> 16),    acc[5]);
    acc[6] = fmaf(wgt, bf2f(u.w & 0xffff), acc[6]);
    acc[7] = fmaf(wgt, bf2f(u.w >> 16),    acc[7]);
}

template <int H, int D, bool RELU, bool FUSE2>
__global__ __launch_bounds__(256) void fagg_k(const unsigned short* __restrict__ ft,
                                              const float* __restrict__ el,
                                              const float* __restrict__ er,
                                              const int* __restrict__ offsets,
                                              const int* __restrict__ csr_src,
                                              const float* __restrict__ bias,
                                              float* __restrict__ out, int n_nodes,
                                              unsigned short* __restrict__ oh,
                                              unsigned short* __restrict__ ol,
                                              const float* __restrict__ wl2,
                                              float* __restrict__ el2,
                                              float* __restrict__ er2) {
    constexpr int HD = H * D;
    constexpr int LPE = HD / 8;    // lanes per edge-row (16B/lane): 32 (L1), 16 (L2)
    constexpr int EPI = 64 / LPE;  // edges per wave-load: 2 (L1), 4 (L2)
    constexpr int SH = (HD == 256) ? 9 : 8;   // log2(row bytes)
    const int lane = threadIdx.x & 63;
    const int w = threadIdx.x >> 6;
    const int n = blockIdx.x * 4 + w;
    __shared__ int   s_src[4][64];
    __shared__ float s_a[4][64 * H];
    if (n >= n_nodes) return;
    const int off = offsets[n];
    const int deg = offsets[n + 1] - off;
    const int lane_sub = lane & (LPE - 1);
    const int q = lane / LPE;
    const int c0 = lane_sub * 8;
    const int h_of = c0 / D;
    const unsigned lsub16 = (unsigned)(lane_sub * 16);
    const char* fb = (const char*)ft;
    const char* eb = (const char*)el;

    float ern[H];
    #pragma unroll
    for (int h = 0; h < H; h++) ern[h] = er[n * H + h];

    float acc[8];
    #pragma unroll
    for (int t = 0; t < 8; t++) acc[t] = 0.f;

    const int* s_src_w = s_src[w];
    const float* s_a_w = s_a[w];

    if (deg <= 64) {
        // ---- fast path ----
        const bool act = lane < deg;
        int sv = act ? csr_src[off + lane] : 0;
        s_src[w][lane] = sv;
        float evr[H];
        if constexpr (H == 4) {
            float4 e4 = *(const float4*)(eb + ((unsigned)sv << 4));
            evr[0] = e4.x; evr[1] = e4.y; evr[2] = e4.z; evr[3] = e4.w;
        } else {
            evr[0] = *(const float*)(eb + ((unsigned)sv << 2));
        }
        const int rc = (deg + EPI - 1) & ~(EPI - 1);
        const int nl = rc / EPI;               // loads per lane (<= 32 L1, <= 16 L2)
        const int nl0 = nl < 16 ? nl : 16;     // main unrolled region
        uint4 vv[8];
        // issue first 8 gathers (latency hidden under softmax)
        #pragma unroll
        for (int i = 0; i < 8; i++) {
            if (i < nl0) {
                unsigned bo = ((unsigned)s_src_w[i * EPI + q] << SH) + lsub16;
                vv[i] = *(const uint4*)(fb + bo);
            }
        }
        // softmax
        float ev[H], m[H];
        #pragma unroll
        for (int h = 0; h < H; h++) {
            float t = evr[h] + ern[h];
            t = t > 0.f ? t : NEG_SLOPE * t;
            ev[h] = act ? t : -1e30f;
            m[h] = ev[h];
        }
        #pragma unroll
        for (int h = 0; h < H; h++)
            for (int o = 32; o > 0; o >>= 1) m[h] = fmaxf(m[h], __shfl_xor(m[h], o));
        float ex[H], sm[H];
        #pragma unroll
        for (int h = 0; h < H; h++) { ex[h] = act ? __expf(ev[h] - m[h]) : 0.f; sm[h] = ex[h]; }
        #pragma unroll
        for (int h = 0; h < H; h++)
            for (int o = 32; o > 0; o >>= 1) sm[h] += __shfl_xor(sm[h], o);
        #pragma unroll
        for (int h = 0; h < H; h++)
            s_a[w][lane * H + h] = ex[h] * (sm[h] > 0.f ? 1.f / sm[h] : 0.f);
        // consume with rolling prefetch (all indices compile-time)
        #pragma unroll
        for (int i = 0; i < 16; i++) {
            if (i < nl0) {
                float wt = s_a_w[(i * EPI + q) * H + h_of];
                fma8(acc, wt, vv[i & 7]);
                if (i + 8 < nl0) {
                    unsigned bo = ((unsigned)s_src_w[(i + 8) * EPI + q] << SH) + lsub16;
                    vv[i & 7] = *(const uint4*)(fb + bo);
                }
            }
        }
        // residual (deg > 32 for L1; never for L2) — rare, simple loop
        for (int e = 16 * EPI + q; e < rc; e += EPI) {
            unsigned bo = ((unsigned)s_src_w[e] << SH) + lsub16;
            uint4 v = *(const uint4*)(fb + bo);
            fma8(acc, s_a_w[e * H + h_of], v);
        }
    } else {
        // ---- rare slow path: two-pass softmax, then 64-edge chunks ----
        float m[H];
        #pragma unroll
        for (int h = 0; h < H; h++) m[h] = -1e30f;
        for (int i = lane; i < deg; i += 64) {
            int sv = csr_src[off + i];
            if constexpr (H == 4) {
                float4 e4 = ((const float4*)el)[sv];
                float tmp[4] = {e4.x, e4.y, e4.z, e4.w};
                #pragma unroll
                for (int h = 0; h < 4; h++) {
                    float t = tmp[h] + ern[h];
                    t = t > 0.f ? t : NEG_SLOPE * t;
                    m[h] = fmaxf(m[h], t);
                }
            } else {
                float t = el[sv] + ern[0];
                t = t > 0.f ? t : NEG_SLOPE * t;
                m[0] = fmaxf(m[0], t);
            }
        }
        #pragma unroll
        for (int h = 0; h < H; h++)
            for (int o = 32; o > 0; o >>= 1) m[h] = fmaxf(m[h], __shfl_xor(m[h], o));
        float sm[H];
        #pragma unroll
        for (int h = 0; h < H; h++) sm[h] = 0.f;
        for (int i = lane; i < deg; i += 64) {
            int sv = csr_src[off + i];
            if constexpr (H == 4) {
                float4 e4 = ((const float4*)el)[sv];
                float tmp[4] = {e4.x, e4.y, e4.z, e4.w};
                #pragma unroll
                for (int h = 0; h < 4; h++) {
                    float t = tmp[h] + ern[h];
                    t = t > 0.f ? t : NEG_SLOPE * t;
                    sm[h] += __expf(t - m[h]);
                }
            } else {
                float t = el[sv] + ern[0];
                t = t > 0.f ? t : NEG_SLOPE * t;
                sm[0] += __expf(t - m[0]);
            }
        }
        #pragma unroll
        for (int h = 0; h < H; h++)
            for (int o = 32; o > 0; o >>= 1) sm[h] += __shfl_xor(sm[h], o);
        float inv[H];
        #pragma unroll
        for (int h = 0; h < H; h++) inv[h] = (sm[h] > 0.f) ? (1.f / sm[h]) : 0.f;
        for (int base = 0; base < deg; base += 64) {
            const bool act2 = base + lane < deg;
            int sv = act2 ? csr_src[off + base + lane] : 0;
            s_src[w][lane] = sv;
            float exh[H];
            if constexpr (H == 4) {
                float4 e4 = ((const float4*)el)[sv];
                float tmp[4] = {e4.x, e4.y, e4.z, e4.w};
                #pragma unroll
                for (int h = 0; h < 4; h++) {
                    float t = tmp[h] + ern[h];
                    t = t > 0.f ? t : NEG_SLOPE * t;
                    exh[h] = act2 ? __expf(t - m[h]) * inv[h] : 0.f;
                }
            } else {
                float t = el[sv] + ern[0];
                t = t > 0.f ? t : NEG_SLOPE * t;
                exh[0] = act2 ? __expf(t - m[0]) * inv[0] : 0.f;
            }
            #pragma unroll
            for (int h = 0; h < H; h++) s_a[w][lane * H + h] = exh[h];
            int cnt = min(64, deg - base);
            int rc2 = (cnt + EPI - 1) & ~(EPI - 1);
            for (int e = q; e < rc2; e += EPI) {
                unsigned bo = ((unsigned)s_src_w[e] << SH) + lsub16;
                uint4 v = *(const uint4*)(fb + bo);
                fma8(acc, s_a_w[e * H + h_of], v);
            }
        }
    }

    // cross-lane combine: edge sub-groups fold into lanes [0, LPE)
    #pragma unroll
    for (int t = 0; t < 8; t++) {
        #pragma unroll
        for (int s = LPE; s < 64; s <<= 1) acc[t] += __shfl_xor(acc[t], s);
    }
    if (lane < LPE) {
        float4 b0 = ((const float4*)bias)[lane * 2];
        float4 b1 = ((const float4*)bias)[lane * 2 + 1];
        float v[8] = {acc[0] + b0.x, acc[1] + b0.y, acc[2] + b0.z, acc[3] + b0.w,
                      acc[4] + b1.x, acc[5] + b1.y, acc[6] + b1.z, acc[7] + b1.w};
        if (RELU) {
            #pragma unroll
            for (int t = 0; t < 8; t++) v[t] = fmaxf(v[t], 0.f);
        }
        if constexpr (FUSE2) {
            unsigned short hh[8], ll[8];
            #pragma unroll
            for (int t = 0; t < 8; t++) {
                hh[t] = f2bf(v[t]);
                ll[t] = f2bf(v[t] - bf2f(hh[t]));
            }
            uint4 hv, lv;
            hv.x = (unsigned)hh[0] | ((unsigned)hh[1] << 16);
            hv.y = (unsigned)hh[2] | ((unsigned)hh[3] << 16);
            hv.z = (unsigned)hh[4] | ((unsigned)hh[5] << 16);
            hv.w = (unsigned)hh[6] | ((unsigned)hh[7] << 16);
            lv.x = (unsigned)ll[0] | ((unsigned)ll[1] << 16);
            lv.y = (unsigned)ll[2] | ((unsigned)ll[3] << 16);
            lv.z = (unsigned)ll[4] | ((unsigned)ll[5] << 16);
            lv.w = (unsigned)ll[6] | ((unsigned)ll[7] << 16);
            ((uint4*)(oh + (size_t)n * HD))[lane] = hv;
            ((uint4*)(ol + (size_t)n * HD))[lane] = lv;
            float pa = 0.f, pb = 0.f;
            #pragma unroll
            for (int t = 0; t < 8; t++) {
                float2 wv = ((const float2*)wl2)[lane * 8 + t];
                pa = fmaf(v[t], wv.x, pa);
                pb = fmaf(v[t], wv.y, pb);
            }
            #pragma unroll
            for (int o = 16; o > 0; o >>= 1) {
                pa += __shfl_xor(pa, o);
                pb += __shfl_xor(pb, o);
            }
            if (lane == 0) { el2[n] = pa; er2[n] = pb; }
        } else {
            float4 o0{v[0], v[1], v[2], v[3]};
            float4 o1{v[4], v[5], v[6], v[7]};
            float4* op = (float4*)out + (size_t)n * (HD / 4) + lane * 2;
            op[0] = o0;
            op[1] = o1;
        }
    }
}

// ---------------- launch ----------------

extern "C" void kernel_launch(void* const* d_in, const int* in_sizes, int n_in,
                              void* d_out, int out_size, void* d_ws, size_t ws_size,
                              hipStream_t stream) {
    const float* feat    = (const float*)d_in[0];
    const int*   src     = (const int*)d_in[1];
    const int*   dst     = (const int*)d_in[2];
    const float* W1      = (const float*)d_in[3];
    const float* attn_l1 = (const float*)d_in[4];
    const float* attn_r1 = (const float*)d_in[5];
    const float* bias1   = (const float*)d_in[6];
    const float* W2      = (const float*)d_in[7];
    const float* attn_l2 = (const float*)d_in[8];
    const float* attn_r2 = (const float*)d_in[9];
    const float* bias2   = (const float*)d_in[10];
    float* out = (float*)d_out;

    const int N = in_sizes[0] / 256;   // 50000
    const int E = in_sizes[1];         // 800000
    const int NB = (N + 1023) / 1024;  // 49 (<= 64 for lookback wave)

    char* ws = (char*)d_ws;
    size_t o = 0;
    auto alloc = [&](size_t bytes) -> void* {
        void* p = ws + o;
        o = (o + bytes + 255) & ~(size_t)255;
        return p;
    };
    int* counts  = (int*)alloc((size_t)(N + 64) * 4);
    int* flags   = counts + N;
    int* cursor  = (int*)alloc((size_t)N * 4);
    int* offsets = (int*)alloc((size_t)(N + 1) * 4);
    int* csr_src = (int*)alloc((size_t)E * 4);
    float* wl1 = (float*)alloc(256 * 8 * 4);
    float* wl2 = (float*)alloc(256 * 2 * 4);
    float* el1 = (float*)alloc((size_t)N * 4 * 4);
    float* er1 = (float*)alloc((size_t)N * 4 * 4);
    float* el2 = (float*)alloc((size_t)N * 4);
    float* er2 = (float*)alloc((size_t)N * 4);
    unsigned short* ft1b = (unsigned short*)alloc((size_t)N * 256 * 2);
    unsigned short* Ah   = (unsigned short*)alloc((size_t)N * 256 * 2);
    unsigned short* Al   = (unsigned short*)alloc((size_t)N * 256 * 2);
    unsigned short* Bt1h = (unsigned short*)alloc((size_t)256 * 256 * 2);
    unsigned short* Bt1l = (unsigned short*)alloc((size_t)256 * 256 * 2);
    unsigned short* Bt2h = (unsigned short*)alloc((size_t)128 * 256 * 2);
    unsigned short* Bt2l = (unsigned short*)alloc((size_t)128 * 256 * 2);
    unsigned short* ft2b = ft1b;   // ft1b dead after layer-1 aggregation
    unsigned short* h1h  = Ah;     // feat split-bf16 dead after layer-1 GEMM
    unsigned short* h1l  = Al;

    hipMemsetAsync(counts, 0, (size_t)(N + 64) * 4, stream);
    count_wl_k<<<7 + (E + 255) / 256, 256, 0, stream>>>(dst, counts, E,
        W1, attn_l1, attn_r1, W2, attn_l2, attn_r2, wl1, wl2, Bt1h, Bt1l, Bt2h, Bt2l);
    scan_k<<<NB, 1024, 0, stream>>>(counts, flags, offsets, cursor, N);
    fill_csr_k<<<(E + 255) / 256, 256, 0, stream>>>(src, dst, cursor, csr_src, E);
    prep_k<<<(N + 3) / 4, 256, 0, stream>>>(feat, wl1, Ah, Al, el1, er1, N);

    // layer 1: H=4, D=64
    gemm_k<<<dim3(4, (N + 127) / 128), 256, 0, stream>>>(Ah, Al, Bt1h, Bt1l, ft1b, N, 256);
    fagg_k<4, 64, true, true><<<(N + 3) / 4, 256, 0, stream>>>(ft1b, el1, er1, offsets, csr_src,
                                                               bias1, nullptr, N,
                                                               h1h, h1l, wl2, el2, er2);

    // layer 2: H=1, D=128
    gemm_k<<<dim3(2, (N + 127) / 128), 256, 0, stream>>>(h1h, h1l, Bt2h, Bt2l, ft2b, N, 128);
    fagg_k<1, 128, false, false><<<(N + 3) / 4, 256, 0, stream>>>(ft2b, el2, er2, offsets, csr_src,
                                                                  bias2, out, N,
                                                                  nullptr, nullptr, nullptr,
                                                                  nullptr, nullptr);
}